// Round 1
// baseline (1038.121 us; speedup 1.0000x reference)
//
#include <hip/hip_runtime.h>

#define T_STEPS 64
#define BATCH   16
#define HEIGHT  260
#define WIDTH   346
#define H_S     65
#define W_S     86
#define HW      (H_S * W_S)          // 5590
#define FRAME   (2 * HEIGHT * WIDTH) // elems per (t,b) frame

// ---------------------------------------------------------------------------
// Kernel 1: 4x4 mean pool (crop to 260x344) + 2-ch 3x3 conv + relu -> exc
// One block per (t,b) frame. Pooled tile lives in LDS with a zero halo ring.
// ---------------------------------------------------------------------------
__global__ __launch_bounds__(256) void k_pool_exc(const float* __restrict__ x,
                                                  const float* __restrict__ exc_w,
                                                  float* __restrict__ exc)
{
    __shared__ float sp[2][H_S + 2][W_S + 2];   // [2][67][88] = 47168 B
    const int tb  = blockIdx.x;                 // t*BATCH + b
    const int tid = threadIdx.x;
    const float* fr = x + (size_t)tb * FRAME;

    // zero the 1-wide halo ring (612 elements total)
    for (int k = tid; k < 612; k += 256) {
        int c = k / 306, k2 = k - c * 306;
        int row, col;
        if (k2 < 176) { row = (k2 < 88) ? 0 : (H_S + 1); col = k2 % 88; }
        else { int k3 = k2 - 176; row = 1 + (k3 % H_S); col = (k3 < H_S) ? 0 : (W_S + 1); }
        sp[c][row][col] = 0.0f;
    }

    // pooling: 2*5590 outputs, 16 input floats each (as 8 float2 loads)
    for (int idx = tid; idx < 2 * HW; idx += 256) {
        int c = idx / HW;
        int r = idx - c * HW;
        int i = r / W_S;
        int j = r - i * W_S;
        const float* base = fr + c * (HEIGHT * WIDTH) + (4 * i) * WIDTH + 4 * j;
        float s = 0.0f;
        #pragma unroll
        for (int rr = 0; rr < 4; ++rr) {
            const float2* p2 = (const float2*)(base + rr * WIDTH); // 8B aligned (even elem offset)
            float2 a = p2[0], b = p2[1];
            s += (a.x + a.y) + (b.x + b.y);
        }
        sp[c][i + 1][j + 1] = s * (1.0f / 16.0f);
    }
    __syncthreads();

    float w[18];
    #pragma unroll
    for (int k = 0; k < 18; ++k) w[k] = exc_w[k];

    float* out = exc + (size_t)tb * HW;
    for (int idx = tid; idx < HW; idx += 256) {
        int i = idx / W_S, j = idx - i * W_S;
        float acc = 0.0f;
        #pragma unroll
        for (int c = 0; c < 2; ++c)
            #pragma unroll
            for (int di = 0; di < 3; ++di)
                #pragma unroll
                for (int dj = 0; dj < 3; ++dj)
                    acc += sp[c][i + di][j + dj] * w[c * 9 + di * 3 + dj];
        out[idx] = fmaxf(acc, 0.0f);
    }
}

// ---------------------------------------------------------------------------
// Kernel 2: inh = conv7x7(exc[t-1]) (zeros at t=0); lgmd = exc[t] + inh
// One block per (t,b) frame; exc[t-1] staged in LDS with 3-wide zero halo.
// ---------------------------------------------------------------------------
__global__ __launch_bounds__(256) void k_inh_lgmd(const float* __restrict__ exc,
                                                  const float* __restrict__ inh_w,
                                                  float* __restrict__ lgmd)
{
    __shared__ float le[H_S + 6][W_S + 6];      // [71][92] = 26128 B
    const int tb  = blockIdx.x;
    const int t   = tb / BATCH;
    const int b   = tb - t * BATCH;
    const int tid = threadIdx.x;

    for (int k = tid; k < (H_S + 6) * (W_S + 6); k += 256) ((float*)le)[k] = 0.0f;
    __syncthreads();
    if (t > 0) {
        const float* ep = exc + (size_t)((t - 1) * BATCH + b) * HW;
        for (int idx = tid; idx < HW; idx += 256) {
            int i = idx / W_S, j = idx - i * W_S;
            le[i + 3][j + 3] = ep[idx];
        }
    }
    __syncthreads();

    float iw[49];
    #pragma unroll
    for (int k = 0; k < 49; ++k) iw[k] = inh_w[k];

    const float* ec  = exc  + (size_t)tb * HW;
    float*       out = lgmd + (size_t)tb * HW;
    for (int idx = tid; idx < HW; idx += 256) {
        int i = idx / W_S, j = idx - i * W_S;
        float acc = ec[idx];
        #pragma unroll
        for (int di = 0; di < 7; ++di)
            #pragma unroll
            for (int dj = 0; dj < 7; ++dj)
                acc += le[i + di][j + dj] * iw[di * 7 + dj];
        out[idx] = acc;
    }
}

// ---------------------------------------------------------------------------
// Kernel 3: per-pixel membrane scan over t; writes spikes + dcmd reduction.
// grid = (ceil(HW/256), BATCH). dcmd region must be pre-zeroed.
// ---------------------------------------------------------------------------
__global__ __launch_bounds__(256) void k_scan(const float* __restrict__ lgmd,
                                              const float* __restrict__ dcmd_w,
                                              float* __restrict__ dcmd,   // d_out[0..1023]
                                              float* __restrict__ spk)    // d_out+1024
{
    const int b   = blockIdx.y;
    const int idx = blockIdx.x * 256 + threadIdx.x;
    const bool act = (idx < HW);
    const float absw = act ? fabsf(dcmd_w[idx]) : 0.0f;
    __shared__ float red[4];

    float v = 0.0f;
    for (int t = 0; t < T_STEPS; ++t) {
        const size_t off = (size_t)(t * BATCH + b) * HW;
        float lg = act ? lgmd[off + idx] : 0.0f;
        v = v + (lg - v) * 0.5f;
        float s = (v - 1.0f >= 0.0f) ? 1.0f : 0.0f;
        v = v * (1.0f - s);
        if (act) spk[off + idx] = s;

        float c = s * absw;
        #pragma unroll
        for (int o = 32; o > 0; o >>= 1) c += __shfl_down(c, o, 64);
        const int lane = threadIdx.x & 63, wid = threadIdx.x >> 6;
        if (lane == 0) red[wid] = c;
        __syncthreads();
        if (threadIdx.x == 0) {
            float tot = red[0] + red[1] + red[2] + red[3];
            atomicAdd(&dcmd[t * BATCH + b], tot);
        }
        __syncthreads();   // before red[] reuse next t
    }
}

extern "C" void kernel_launch(void* const* d_in, const int* in_sizes, int n_in,
                              void* d_out, int out_size, void* d_ws, size_t ws_size,
                              hipStream_t stream)
{
    const float* x      = (const float*)d_in[0];
    const float* exc_w  = (const float*)d_in[1];
    const float* inh_w  = (const float*)d_in[2];
    const float* dcmd_w = (const float*)d_in[3];
    float* out = (float*)d_out;

    float* ws_exc  = (float*)d_ws;                         // T*B*HW f32 = 22.9 MB
    float* ws_lgmd = ws_exc + (size_t)T_STEPS * BATCH * HW; // another 22.9 MB

    // dcmd region is accumulated via atomics -> zero it (harness poisons 0xAA)
    hipMemsetAsync(d_out, 0, T_STEPS * BATCH * sizeof(float), stream);

    k_pool_exc<<<T_STEPS * BATCH, 256, 0, stream>>>(x, exc_w, ws_exc);
    k_inh_lgmd<<<T_STEPS * BATCH, 256, 0, stream>>>(ws_exc, inh_w, ws_lgmd);
    dim3 g3((HW + 255) / 256, BATCH);
    k_scan<<<g3, 256, 0, stream>>>(ws_lgmd, dcmd_w, out, out + T_STEPS * BATCH);
}